// Round 7
// baseline (184.493 us; speedup 1.0000x reference)
//
#include <hip/hip_runtime.h>

#define DEV static __device__ __forceinline__

typedef float f32x4 __attribute__((ext_vector_type(4)));
typedef int i32x4 __attribute__((ext_vector_type(4)));
typedef __bf16 bf16x8 __attribute__((ext_vector_type(8)));
typedef unsigned short u16x8 __attribute__((ext_vector_type(8)));
typedef unsigned short u16x4 __attribute__((ext_vector_type(4)));

#define MFMA(a, b, c) __builtin_amdgcn_mfma_f32_16x16x32_bf16((a), (b), (c), 0, 0, 0)

// fine-grained barriers: counted vmcnt (never a just-issued drain) + s_barrier.
#define WAIT5_BARRIER() asm volatile("s_waitcnt vmcnt(5)\n\ts_barrier" ::: "memory")
#define VM0_BARRIER()   asm volatile("s_waitcnt vmcnt(0)\n\ts_barrier" ::: "memory")
#define LGKM_BARRIER()  asm volatile("s_waitcnt lgkmcnt(0)\n\ts_barrier" ::: "memory")
#define VM_DRAIN()      asm volatile("s_waitcnt vmcnt(0)" ::: "memory")

// B=8, T=2048, C=1024, H=64
#define TT 2048
#define CE 1024
#define HS 64

// ws layout (ushort elements unless noted). Total ~16.7 MB; round-6 profile
// shows the harness poisons a 256 MiB workspace arena, so this is safe.
#define WBT_E 0                   // [3][64 n][1024 k] bf16 (Wq scaled by log2e/32)
#define Q_E   196608              // [B*T][64] bf16
#define K_E   (Q_E + 1048576)
#define VT_E  (K_E + 1048576)     // [B][64 h][2048 t] bf16
#define PO_E  (VT_E + 1048576)    // [1152 slots][64 row][64 h] bf16 partial O
#define PML_E (PO_E + 4718592)    // float [1152][64 row][2] {m,l}

DEV unsigned short cvt_bf16(float f) {
    unsigned int u = __builtin_bit_cast(unsigned int, f);
    u += 0x7FFFu + ((u >> 16) & 1u);   // RNE (finite inputs)
    return (unsigned short)(u >> 16);
}

DEV float bf2f(unsigned short v) {
    unsigned int u = ((unsigned int)v) << 16;
    return __builtin_bit_cast(float, u);
}

DEV bf16x8 ld_bf8(const unsigned short* p) {
    union { u16x8 u; bf16x8 b; } v;
    v.u = *(const u16x8*)p;
    return v.b;
}

DEV bf16x8 as_bf8(u16x8 u) {
    union { u16x8 u; bf16x8 b; } v;
    v.u = u;
    return v.b;
}

// async global->LDS, 16B/lane; LDS dst is WAVE-UNIFORM base (+lane*16 by HW)
DEV void glds16(const void* g, void* l) {
    __builtin_amdgcn_global_load_lds(
        (const __attribute__((address_space(1))) void*)g,
        (__attribute__((address_space(3))) void*)l, 16, 0, 0);
}

// ---------------- kernel 1: W fp32 -> bf16 transposed [n][k] ----------------
__global__ __launch_bounds__(256) void wconv_kernel(
        const float* __restrict__ Wq, const float* __restrict__ Wk,
        const float* __restrict__ Wv, unsigned short* __restrict__ wbt) {
    __shared__ unsigned short Tr[64 * 72];
    const int blk = blockIdx.x;
    const int head = blk >> 4, kt = blk & 15;
    const int k0 = kt * 64;
    const float* W = (head == 0) ? Wq : ((head == 1) ? Wk : Wv);
    const float sc = (head == 0) ? 0.045084220027780106f : 1.0f;  // log2(e)/32
    const int t = threadIdx.x;
    const int rrow = t >> 4, c4 = (t & 15) * 4;
    for (int i = 0; i < 4; ++i) {
        int krow = rrow + i * 16;
        f32x4 f = *(const f32x4*)(W + (size_t)(k0 + krow) * 64 + c4);
        Tr[(c4 + 0) * 72 + krow] = cvt_bf16(f[0] * sc);
        Tr[(c4 + 1) * 72 + krow] = cvt_bf16(f[1] * sc);
        Tr[(c4 + 2) * 72 + krow] = cvt_bf16(f[2] * sc);
        Tr[(c4 + 3) * 72 + krow] = cvt_bf16(f[3] * sc);
    }
    __syncthreads();
    const int n = t >> 2, off = (t & 3) * 16;
    u16x8 a0 = *(const u16x8*)&Tr[n * 72 + off];
    u16x8 a1 = *(const u16x8*)&Tr[n * 72 + off + 8];
    unsigned short* dst = wbt + head * 65536 + n * 1024 + k0 + off;
    *(u16x8*)dst = a0;
    *(u16x8*)(dst + 8) = a1;
}

// ---------------- kernel 2: projection q,k = x@W; v transposed -> vt --------
// Big-slot structure (round-3): 256 blocks (1/CU) x 8 waves; block tile
// 64 rows x 192 cols, K-step 64, 16 slots. 40 glds/slot = uniform 5/wave,
// 3 LDS buffers (120 KB), depth-2 ring, vmcnt(5)+barrier.
__global__ __launch_bounds__(512, 2) void proj_kernel(
        const float* __restrict__ x, const unsigned short* __restrict__ wbt,
        unsigned short* __restrict__ qws, unsigned short* __restrict__ kws,
        unsigned short* __restrict__ vtws) {
    __shared__ __align__(16) float Xt0[4096], Xt1[4096], Xt2[4096];          // 3x16 KB
    __shared__ __align__(16) unsigned short Wt0[12288], Wt1[12288], Wt2[12288]; // 3x24 KB
    __shared__ __align__(16) unsigned short TT2[64 * 72];  // v-transpose scratch

    const int t = threadIdx.x;
    const int lane = t & 63, w = t >> 6;        // w in 0..7
    const int quad = lane >> 4, c = lane & 15;
    const int wm = w & 1, wn = w >> 1;          // 32-row half, 48-col quarter
    const int t0 = blockIdx.x * 64;
    const int ck7 = c & 7;

    // ---- staging geometry (content chunk = phys chunk ^ (row&7 | col&7)) --
    // x: glds g covers 4 rows (local rows w*8+g*4 .. +3), 16 chunks of 16B
    const int sxr = lane >> 4;                         // row-in-group 0..3
    const int sxc0 = (lane & 15) ^ sxr;                // key (0*4+sxr)&7
    const int sxc1 = (lane & 15) ^ ((4 + sxr) & 7);    // key (4+sxr)&7
    const float* xg0 = x + (size_t)(t0 + w * 8 + 0 + sxr) * CE + sxc0 * 4;
    const float* xg1 = x + (size_t)(t0 + w * 8 + 4 + sxr) * CE + sxc1 * 4;
    // W: glds g covers 8 cols (local cols w*24+g*8 .. +7), 8 chunks of 16B
    const int swc = lane >> 3;                         // col-in-group 0..7
    const int swk = (lane & 7) ^ swc;                  // key = col&7 = swc
    const unsigned short* wg0 = wbt + (size_t)(w * 24 + 0 + swc) * 1024 + swk * 8;
    const unsigned short* wg1 = wbt + (size_t)(w * 24 + 8 + swc) * 1024 + swk * 8;
    const unsigned short* wg2 = wbt + (size_t)(w * 24 + 16 + swc) * 1024 + swk * 8;

#define PSTAGE(XD, WD, ks) { \
    const int kf = (ks) * 64; \
    glds16(xg0 + kf, &XD[(w * 8 + 0) * 64]); \
    glds16(xg1 + kf, &XD[(w * 8 + 4) * 64]); \
    glds16(wg0 + kf, &WD[(w * 24 + 0) * 64]); \
    glds16(wg1 + kf, &WD[(w * 24 + 8) * 64]); \
    glds16(wg2 + kf, &WD[(w * 24 + 16) * 64]); }

    f32x4 acc[2][3] = {};

    // prologue: stage k-slices 0,1 into buffers 0,1 (10 glds/wave in flight)
    PSTAGE(Xt0, Wt0, 0)
    PSTAGE(Xt1, Wt1, 1)
    // no barrier: first PITER's WAIT5_BARRIER covers buffer 0 + syncs waves

#define PITER(step, XT, WT, XD, WD) { \
    WAIT5_BARRIER(); \
    bf16x8 af[2][2]; \
    _Pragma("unroll") for (int rf = 0; rf < 2; ++rf) \
    _Pragma("unroll") for (int kk = 0; kk < 2; ++kk) { \
        const int row = wm * 32 + rf * 16 + c; \
        const int lc = kk * 8 + quad * 2; \
        f32x4 v0 = *(const f32x4*)&XT[row * 64 + ((lc ^ ck7) * 4)]; \
        f32x4 v1 = *(const f32x4*)&XT[row * 64 + (((lc + 1) ^ ck7) * 4)]; \
        u16x8 ap; \
        _Pragma("unroll") for (int j = 0; j < 4; ++j) { \
            ap[j] = cvt_bf16(v0[j]); ap[4 + j] = cvt_bf16(v1[j]); } \
        af[rf][kk] = as_bf8(ap); \
    } \
    _Pragma("unroll") for (int nt = 0; nt < 3; ++nt) \
    _Pragma("unroll") for (int kk = 0; kk < 2; ++kk) { \
        const int col = wn * 48 + nt * 16 + c; \
        bf16x8 bb = ld_bf8(&WT[col * 64 + (((kk * 4 + quad) ^ ck7) * 8)]); \
        acc[0][nt] = MFMA(af[0][kk], bb, acc[0][nt]); \
        acc[1][nt] = MFMA(af[1][kk], bb, acc[1][nt]); \
    } \
    PSTAGE(XD, WD, (((step) + 2) & 15)) }

    for (int s = 0; s < 15; s += 3) {
        PITER(s + 0, Xt0, Wt0, Xt2, Wt2)
        PITER(s + 1, Xt1, Wt1, Xt0, Wt0)
        PITER(s + 2, Xt2, Wt2, Xt1, Wt1)
    }
    PITER(15, Xt0, Wt0, Xt2, Wt2)   // tail: stages dummy (slice wraps to 1)
#undef PITER
#undef PSTAGE

    // epilogue: q,k direct; v transposed via LDS (64 h x 64 t, stride 72)
#pragma unroll
    for (int rf = 0; rf < 2; ++rf) {
#pragma unroll
        for (int nt = 0; nt < 3; ++nt) {
            int col = wn * 48 + nt * 16 + c;
            f32x4 a = acc[rf][nt];
#pragma unroll
            for (int r4 = 0; r4 < 4; ++r4) {
                int row = wm * 32 + rf * 16 + quad * 4 + r4;
                size_t tg = (size_t)(t0 + row);
                unsigned short hv = cvt_bf16(a[r4]);
                if (col < 64)       qws[tg * HS + col] = hv;
                else if (col < 128) kws[tg * HS + col - 64] = hv;
                else                TT2[(col - 128) * 72 + row] = hv;
            }
        }
    }
    __syncthreads();   // full drain: also retires the tail dummy glds
    {
        int h = t >> 3, off = (t & 7) * 8;
        u16x8 v = *(const u16x8*)&TT2[h * 72 + off];
        int b = t0 >> 11, tl0 = t0 & 2047;
        *(u16x8*)(vtws + (size_t)(b * 64 + h) * TT + tl0 + off) = v;
    }
}

// ---------------- kernel 3: flash, ring-2, balanced 4-tile chunks ----------
// 1152 blocks = 8 b x 144 chunks. Chunk = up to 4 kv-tiles of one q-tile:
// q-tiles [4g, 4g+3] each own g+1 chunks (all non-empty; exactly covers
// ceil((qt+1)/4)). Block durations 1..4 iters -> balanced makespan
// (~16.5 mean iters/CU + <=4 tail) and 4.5 blocks/CU in flight (3 LDS-
// resident at 42 KB) for concurrent glds streams. Ring-2 stage-at-top:
// per iter {vmcnt(0)+barrier (drains loads issued a FULL iteration ago),
// stage j+1 into opposite buffer, compute j}.
__global__ __launch_bounds__(256) void flash_kernel(
        const unsigned short* __restrict__ qws, const unsigned short* __restrict__ kws,
        const unsigned short* __restrict__ vtws, const int* __restrict__ pmask,
        unsigned short* __restrict__ pO, float* __restrict__ pml) {
    __shared__ __align__(16) unsigned short Kt0[4096], Kt1[4096];
    __shared__ __align__(16) unsigned short Vt0[4096], Vt1[4096];
    __shared__ __align__(16) unsigned short Ps[4][1152];  // per-wave P [q16][kv 64+8]
    __shared__ __align__(16) float Bs[256];               // bias for <=4 iters

    const int t = threadIdx.x, blk = blockIdx.x;
    const int b = blk / 144, cid = blk - b * 144;
    // decode cid -> (qt, chunk): group g starts at 2g(g+1), spans 4(g+1)
    int g = 0;
    while (cid >= 2 * (g + 1) * (g + 2)) ++g;   // <=7 iters, block-uniform
    const int off = cid - 2 * g * (g + 1);
    const int qi = off / (g + 1);
    const int chunk = off - qi * (g + 1);
    const int qt = 4 * g + qi;
    const int jbeg = chunk * 4;
    int je = jbeg + 4; if (je > qt + 1) je = qt + 1;
    const int jend = je;
    const int niter = jend - jbeg;              // 1..4

    const int lane = t & 63, w = t >> 6;
    const int quad = lane >> 4, c = lane & 15;

    // staging geometry: instrs i0=2w, i1=2w+1 of 8; row = i*8 + (lane>>3)
    const int srow = lane >> 3, scb = (lane & 7) ^ srow;
    const unsigned short* kg0 = kws + (size_t)(b * TT + 2 * w * 8 + srow) * HS + scb * 8;
    const unsigned short* kg1 = kg0 + (size_t)8 * HS;
    const unsigned short* vg0 = vtws + (size_t)(b * 64 + 2 * w * 8 + srow) * TT + scb * 8;
    const unsigned short* vg1 = vg0 + (size_t)8 * TT;

#define FSTAGE(KD, VD, kv) \
    glds16(kg0 + (size_t)(kv) * HS, &KD[(2 * w + 0) * 512]); \
    glds16(kg1 + (size_t)(kv) * HS, &KD[(2 * w + 1) * 512]); \
    glds16(vg0 + (kv), &VD[(2 * w + 0) * 512]); \
    glds16(vg1 + (kv), &VD[(2 * w + 1) * 512]);

    // Q B-frag (n = qrow = c)
    bf16x8 qf[2];
#pragma unroll
    for (int kk = 0; kk < 2; ++kk)
        qf[kk] = ld_bf8(qws + (size_t)(b * TT + qt * 64 + w * 16 + c) * HS + kk * 32 + quad * 8);

    // fused bias: pad mask ints -> additive float bias in LDS
    {
        int bi = t * 4;
        if (bi < niter * 64) {
            i32x4 pmv = *(const i32x4*)(pmask + b * TT + jbeg * 64 + bi);
            f32x4 bvv;
#pragma unroll
            for (int j = 0; j < 4; ++j) bvv[j] = pmv[j] ? 0.0f : -1e30f;
            *(f32x4*)&Bs[bi] = bvv;
        }
    }

    // prologue: stage iter jbeg into buffer 0 (4 glds/wave in flight)
    FSTAGE(Kt0, Vt0, jbeg * 64)
    LGKM_BARRIER();   // Bs visible; glds drained by first VM0_BARRIER

    f32x4 o[4] = {};
    float m_run = -1e30f, l_run = 0.0f;
    const int ck7 = c & 7;

#define FITER(u, KT, VT, KD, VD) \
    if (j0 + (u) < jend) { \
        const int j = j0 + (u); \
        VM0_BARRIER(); \
        { int jn = j + 1; if (jn > jend - 1) jn = jend - 1; \
          FSTAGE(KD, VD, jn * 64) } \
        f32x4 bv[4]; \
        _Pragma("unroll") for (int nt = 0; nt < 4; ++nt) \
            bv[nt] = *(const f32x4*)&Bs[(j - jbeg) * 64 + nt * 16 + quad * 4]; \
        f32x4 s4[4] = {}; \
        _Pragma("unroll") for (int kk = 0; kk < 2; ++kk) \
        _Pragma("unroll") for (int nt = 0; nt < 4; ++nt) { \
            bf16x8 ka = ld_bf8(&KT[(nt * 16 + c) * 64 + (((kk * 4 + quad) ^ ck7) * 8)]); \
            s4[nt] = MFMA(ka, qf[kk], s4[nt]); } \
        if (j == qt) { \
            const int qrl = w * 16 + c; \
            _Pragma("unroll") for (int nt = 0; nt < 4; ++nt) \
            _Pragma("unroll") for (int r = 0; r < 4; ++r) { \
                int kvl = nt * 16 + quad * 4 + r; \
                s4[nt][r] = (kvl > qrl) ? -1e30f : (s4[nt][r] + bv[nt][r]); } \
        } else { \
            _Pragma("unroll") for (int nt = 0; nt < 4; ++nt) \
            _Pragma("unroll") for (int r = 0; r < 4; ++r) s4[nt][r] += bv[nt][r]; } \
        float mx = s4[0][0]; \
        _Pragma("unroll") for (int nt = 0; nt < 4; ++nt) \
        _Pragma("unroll") for (int r = 0; r < 4; ++r) mx = fmaxf(mx, s4[nt][r]); \
        mx = fmaxf(mx, __shfl_xor(mx, 16, 64)); \
        mx = fmaxf(mx, __shfl_xor(mx, 32, 64)); \
        float mnew = fmaxf(m_run, mx); \
        float al = exp2f(m_run - mnew); \
        m_run = mnew; \
        _Pragma("unroll") for (int nt = 0; nt < 4; ++nt) \
        _Pragma("unroll") for (int r = 0; r < 4; ++r) s4[nt][r] = exp2f(s4[nt][r] - mnew); \
        float rs = 0.0f; \
        _Pragma("unroll") for (int nt = 0; nt < 4; ++nt) \
            rs += (s4[nt][0] + s4[nt][1]) + (s4[nt][2] + s4[nt][3]); \
        rs += __shfl_xor(rs, 16, 64); \
        rs += __shfl_xor(rs, 32, 64); \
        l_run = l_run * al + rs; \
        _Pragma("unroll") for (int ht = 0; ht < 4; ++ht) \
        _Pragma("unroll") for (int r = 0; r < 4; ++r) o[ht][r] *= al; \
        _Pragma("unroll") for (int nt = 0; nt < 4; ++nt) { \
            u16x4 pk; \
            _Pragma("unroll") for (int r = 0; r < 4; ++r) pk[r] = cvt_bf16(s4[nt][r]); \
            *(u16x4*)&Ps[w][c * 72 + nt * 16 + quad * 4] = pk; } \
        bf16x8 p0 = ld_bf8(&Ps[w][c * 72 + quad * 8]); \
        bf16x8 p1 = ld_bf8(&Ps[w][c * 72 + 32 + quad * 8]); \
        _Pragma("unroll") for (int kk = 0; kk < 2; ++kk) { \
            bf16x8 pa = kk ? p1 : p0; \
            _Pragma("unroll") for (int ht = 0; ht < 4; ++ht) { \
                bf16x8 va = ld_bf8(&VT[(ht * 16 + c) * 64 + (((kk * 4 + quad) ^ ck7) * 8)]); \
                o[ht] = MFMA(va, pa, o[ht]); } } \
    }

    for (int j0 = jbeg; j0 < jend; j0 += 2) {
        FITER(0, Kt0, Vt0, Kt1, Vt1)
        FITER(1, Kt1, Vt1, Kt0, Vt0)
    }
#undef FITER
#undef FSTAGE

    VM_DRAIN();   // retire tail glds before LDS dealloc at endpgm

    // ---- store partials: slot = blk; pO [slot][row 64][h 64] ----
    unsigned short* po = pO + (size_t)blk * 4096;
#pragma unroll
    for (int ht = 0; ht < 4; ++ht) {
        u16x4 pk;
#pragma unroll
        for (int r = 0; r < 4; ++r) pk[r] = cvt_bf16(o[ht][r]);
        *(u16x4*)(po + (w * 16 + c) * 64 + ht * 16 + quad * 4) = pk;
    }
    if (quad == 0) {
        pml[(size_t)blk * 128 + (w * 16 + c) * 2] = m_run;
        pml[(size_t)blk * 128 + (w * 16 + c) * 2 + 1] = l_run;
    }
}

// ---------------- kernel 4: combine g+1 chunks -> final output --------------
// 256 blocks (b,qt) x 256 thr. Chunk slots for qt: base = b*144 + 2g(g+1) +
// (qt-4g)*(g+1), count g+1 (g = qt>>2); all non-empty. Two-pass merge (max,
// then weighted sum) to avoid runtime-indexed register arrays.
__global__ __launch_bounds__(256) void combine_kernel(
        const unsigned short* __restrict__ pO, const float* __restrict__ pml,
        float* __restrict__ out) {
    const int blk = blockIdx.x;
    const int qt = blk >> 3, b = blk & 7;
    const int g = qt >> 2;
    const int nc = g + 1;
    const int s0 = b * 144 + 2 * g * (g + 1) + (qt - 4 * g) * (g + 1);
    const int t = threadIdx.x, h = t & 63, rg = t >> 6;
    for (int i = 0; i < 16; ++i) {
        int row = rg + i * 4;
        float M = -3e38f;
        for (int s = 0; s < nc; ++s)
            M = fmaxf(M, pml[(size_t)(s0 + s) * 128 + row * 2]);
        float num = 0.0f, den = 0.0f;
        for (int s = 0; s < nc; ++s) {
            float m = pml[(size_t)(s0 + s) * 128 + row * 2];
            float l = pml[(size_t)(s0 + s) * 128 + row * 2 + 1];
            float ov = bf2f(pO[(size_t)(s0 + s) * 4096 + row * 64 + h]);
            float ww = exp2f(m - M);
            num += ov * ww;
            den += l * ww;
        }
        out[(size_t)(b * TT + qt * 64 + row) * HS + h] = num / den;
    }
}

extern "C" void kernel_launch(void* const* d_in, const int* in_sizes, int n_in,
                              void* d_out, int out_size, void* d_ws, size_t ws_size,
                              hipStream_t stream) {
    const float* x  = (const float*)d_in[0];
    const int* pm   = (const int*)d_in[1];
    const float* Wq = (const float*)d_in[2];
    const float* Wk = (const float*)d_in[3];
    const float* Wv = (const float*)d_in[4];
    float* out = (float*)d_out;

    unsigned short* wsu  = (unsigned short*)d_ws;
    unsigned short* wbt  = wsu + WBT_E;
    unsigned short* qws  = wsu + Q_E;
    unsigned short* kws  = wsu + K_E;
    unsigned short* vtws = wsu + VT_E;
    unsigned short* pO   = wsu + PO_E;
    float* pml           = (float*)(wsu + PML_E);

    wconv_kernel<<<48, 256, 0, stream>>>(Wq, Wk, Wv, wbt);
    proj_kernel<<<256, 512, 0, stream>>>(x, wbt, qws, kws, vtws);
    flash_kernel<<<1152, 256, 0, stream>>>(qws, kws, vtws, pm, pO, pml);
    combine_kernel<<<256, 256, 0, stream>>>(pO, pml, out);
}

// Round 8
// 140.451 us; speedup vs baseline: 1.3136x; 1.3136x over previous
//
#include <hip/hip_runtime.h>

#define DEV static __device__ __forceinline__

typedef float f32x4 __attribute__((ext_vector_type(4)));
typedef int i32x4 __attribute__((ext_vector_type(4)));
typedef __bf16 bf16x8 __attribute__((ext_vector_type(8)));
typedef unsigned short u16x8 __attribute__((ext_vector_type(8)));
typedef unsigned short u16x4 __attribute__((ext_vector_type(4)));

#define MFMA(a, b, c) __builtin_amdgcn_mfma_f32_16x16x32_bf16((a), (b), (c), 0, 0, 0)

// fine-grained barriers: counted vmcnt (never a just-issued drain) + s_barrier.
#define WAIT5_BARRIER() asm volatile("s_waitcnt vmcnt(5)\n\ts_barrier" ::: "memory")
#define VM0_BARRIER()   asm volatile("s_waitcnt vmcnt(0)\n\ts_barrier" ::: "memory")
#define LGKM_BARRIER()  asm volatile("s_waitcnt lgkmcnt(0)\n\ts_barrier" ::: "memory")
#define VM_DRAIN()      asm volatile("s_waitcnt vmcnt(0)" ::: "memory")

// B=8, T=2048, C=1024, H=64
#define TT 2048
#define CE 1024
#define HS 64

// ws layout (ushort elements unless noted). Total ~16.7 MB; round-6 profile
// shows the harness poisons a 256 MiB workspace arena, so this is safe.
#define WBT_E 0                   // [3][64 n][1024 k] bf16 (Wq scaled by log2e/32)
#define Q_E   196608              // [B*T][64] bf16
#define K_E   (Q_E + 1048576)
#define VT_E  (K_E + 1048576)     // [B][64 h][2048 t] bf16
#define PO_E  (VT_E + 1048576)    // [1152 slots][64 row][64 h] bf16 partial O
#define PML_E (PO_E + 4718592)    // float [1152][64 row][2] {m,l}

DEV unsigned short cvt_bf16(float f) {
    unsigned int u = __builtin_bit_cast(unsigned int, f);
    u += 0x7FFFu + ((u >> 16) & 1u);   // RNE (finite inputs)
    return (unsigned short)(u >> 16);
}

DEV float bf2f(unsigned short v) {
    unsigned int u = ((unsigned int)v) << 16;
    return __builtin_bit_cast(float, u);
}

DEV bf16x8 ld_bf8(const unsigned short* p) {
    union { u16x8 u; bf16x8 b; } v;
    v.u = *(const u16x8*)p;
    return v.b;
}

DEV bf16x8 as_bf8(u16x8 u) {
    union { u16x8 u; bf16x8 b; } v;
    v.u = u;
    return v.b;
}

// async global->LDS, 16B/lane; LDS dst is WAVE-UNIFORM base (+lane*16 by HW)
DEV void glds16(const void* g, void* l) {
    __builtin_amdgcn_global_load_lds(
        (const __attribute__((address_space(1))) void*)g,
        (__attribute__((address_space(3))) void*)l, 16, 0, 0);
}

// ---------------- kernel 1: W fp32 -> bf16 transposed [n][k] ----------------
__global__ __launch_bounds__(256) void wconv_kernel(
        const float* __restrict__ Wq, const float* __restrict__ Wk,
        const float* __restrict__ Wv, unsigned short* __restrict__ wbt) {
    __shared__ unsigned short Tr[64 * 72];
    const int blk = blockIdx.x;
    const int head = blk >> 4, kt = blk & 15;
    const int k0 = kt * 64;
    const float* W = (head == 0) ? Wq : ((head == 1) ? Wk : Wv);
    const float sc = (head == 0) ? 0.045084220027780106f : 1.0f;  // log2(e)/32
    const int t = threadIdx.x;
    const int rrow = t >> 4, c4 = (t & 15) * 4;
    for (int i = 0; i < 4; ++i) {
        int krow = rrow + i * 16;
        f32x4 f = *(const f32x4*)(W + (size_t)(k0 + krow) * 64 + c4);
        Tr[(c4 + 0) * 72 + krow] = cvt_bf16(f[0] * sc);
        Tr[(c4 + 1) * 72 + krow] = cvt_bf16(f[1] * sc);
        Tr[(c4 + 2) * 72 + krow] = cvt_bf16(f[2] * sc);
        Tr[(c4 + 3) * 72 + krow] = cvt_bf16(f[3] * sc);
    }
    __syncthreads();
    const int n = t >> 2, off = (t & 3) * 16;
    u16x8 a0 = *(const u16x8*)&Tr[n * 72 + off];
    u16x8 a1 = *(const u16x8*)&Tr[n * 72 + off + 8];
    unsigned short* dst = wbt + head * 65536 + n * 1024 + k0 + off;
    *(u16x8*)dst = a0;
    *(u16x8*)(dst + 8) = a1;
}

// ---------------- kernel 2: projection q,k = x@W; v transposed -> vt --------
// Big-slot structure (round-3): 256 blocks (1/CU) x 8 waves; block tile
// 64 rows x 192 cols, K-step 64, 16 slots. 40 glds/slot = uniform 5/wave,
// 3 LDS buffers (120 KB), depth-2 ring, vmcnt(5)+barrier.
__global__ __launch_bounds__(512, 2) void proj_kernel(
        const float* __restrict__ x, const unsigned short* __restrict__ wbt,
        unsigned short* __restrict__ qws, unsigned short* __restrict__ kws,
        unsigned short* __restrict__ vtws) {
    __shared__ __align__(16) float Xt0[4096], Xt1[4096], Xt2[4096];          // 3x16 KB
    __shared__ __align__(16) unsigned short Wt0[12288], Wt1[12288], Wt2[12288]; // 3x24 KB
    __shared__ __align__(16) unsigned short TT2[64 * 72];  // v-transpose scratch

    const int t = threadIdx.x;
    const int lane = t & 63, w = t >> 6;        // w in 0..7
    const int quad = lane >> 4, c = lane & 15;
    const int wm = w & 1, wn = w >> 1;          // 32-row half, 48-col quarter
    const int t0 = blockIdx.x * 64;
    const int ck7 = c & 7;

    // ---- staging geometry (content chunk = phys chunk ^ (row&7 | col&7)) --
    // x: glds g covers 4 rows (local rows w*8+g*4 .. +3), 16 chunks of 16B
    const int sxr = lane >> 4;                         // row-in-group 0..3
    const int sxc0 = (lane & 15) ^ sxr;                // key (0*4+sxr)&7
    const int sxc1 = (lane & 15) ^ ((4 + sxr) & 7);    // key (4+sxr)&7
    const float* xg0 = x + (size_t)(t0 + w * 8 + 0 + sxr) * CE + sxc0 * 4;
    const float* xg1 = x + (size_t)(t0 + w * 8 + 4 + sxr) * CE + sxc1 * 4;
    // W: glds g covers 8 cols (local cols w*24+g*8 .. +7), 8 chunks of 16B
    const int swc = lane >> 3;                         // col-in-group 0..7
    const int swk = (lane & 7) ^ swc;                  // key = col&7 = swc
    const unsigned short* wg0 = wbt + (size_t)(w * 24 + 0 + swc) * 1024 + swk * 8;
    const unsigned short* wg1 = wbt + (size_t)(w * 24 + 8 + swc) * 1024 + swk * 8;
    const unsigned short* wg2 = wbt + (size_t)(w * 24 + 16 + swc) * 1024 + swk * 8;

#define PSTAGE(XD, WD, ks) { \
    const int kf = (ks) * 64; \
    glds16(xg0 + kf, &XD[(w * 8 + 0) * 64]); \
    glds16(xg1 + kf, &XD[(w * 8 + 4) * 64]); \
    glds16(wg0 + kf, &WD[(w * 24 + 0) * 64]); \
    glds16(wg1 + kf, &WD[(w * 24 + 8) * 64]); \
    glds16(wg2 + kf, &WD[(w * 24 + 16) * 64]); }

    f32x4 acc[2][3] = {};

    // prologue: stage k-slices 0,1 into buffers 0,1 (10 glds/wave in flight)
    PSTAGE(Xt0, Wt0, 0)
    PSTAGE(Xt1, Wt1, 1)
    // no barrier: first PITER's WAIT5_BARRIER covers buffer 0 + syncs waves

#define PITER(step, XT, WT, XD, WD) { \
    WAIT5_BARRIER(); \
    bf16x8 af[2][2]; \
    _Pragma("unroll") for (int rf = 0; rf < 2; ++rf) \
    _Pragma("unroll") for (int kk = 0; kk < 2; ++kk) { \
        const int row = wm * 32 + rf * 16 + c; \
        const int lc = kk * 8 + quad * 2; \
        f32x4 v0 = *(const f32x4*)&XT[row * 64 + ((lc ^ ck7) * 4)]; \
        f32x4 v1 = *(const f32x4*)&XT[row * 64 + (((lc + 1) ^ ck7) * 4)]; \
        u16x8 ap; \
        _Pragma("unroll") for (int j = 0; j < 4; ++j) { \
            ap[j] = cvt_bf16(v0[j]); ap[4 + j] = cvt_bf16(v1[j]); } \
        af[rf][kk] = as_bf8(ap); \
    } \
    _Pragma("unroll") for (int nt = 0; nt < 3; ++nt) \
    _Pragma("unroll") for (int kk = 0; kk < 2; ++kk) { \
        const int col = wn * 48 + nt * 16 + c; \
        bf16x8 bb = ld_bf8(&WT[col * 64 + (((kk * 4 + quad) ^ ck7) * 8)]); \
        acc[0][nt] = MFMA(af[0][kk], bb, acc[0][nt]); \
        acc[1][nt] = MFMA(af[1][kk], bb, acc[1][nt]); \
    } \
    PSTAGE(XD, WD, (((step) + 2) & 15)) }

    for (int s = 0; s < 15; s += 3) {
        PITER(s + 0, Xt0, Wt0, Xt2, Wt2)
        PITER(s + 1, Xt1, Wt1, Xt0, Wt0)
        PITER(s + 2, Xt2, Wt2, Xt1, Wt1)
    }
    PITER(15, Xt0, Wt0, Xt2, Wt2)   // tail: stages dummy (slice wraps to 1)
#undef PITER
#undef PSTAGE

    // epilogue: q,k direct; v transposed via LDS (64 h x 64 t, stride 72)
#pragma unroll
    for (int rf = 0; rf < 2; ++rf) {
#pragma unroll
        for (int nt = 0; nt < 3; ++nt) {
            int col = wn * 48 + nt * 16 + c;
            f32x4 a = acc[rf][nt];
#pragma unroll
            for (int r4 = 0; r4 < 4; ++r4) {
                int row = wm * 32 + rf * 16 + quad * 4 + r4;
                size_t tg = (size_t)(t0 + row);
                unsigned short hv = cvt_bf16(a[r4]);
                if (col < 64)       qws[tg * HS + col] = hv;
                else if (col < 128) kws[tg * HS + col - 64] = hv;
                else                TT2[(col - 128) * 72 + row] = hv;
            }
        }
    }
    __syncthreads();   // full drain: also retires the tail dummy glds
    {
        int h = t >> 3, off = (t & 7) * 8;
        u16x8 v = *(const u16x8*)&TT2[h * 72 + off];
        int b = t0 >> 11, tl0 = t0 & 2047;
        *(u16x8*)(vtws + (size_t)(b * 64 + h) * TT + tl0 + off) = v;
    }
}

// ---------------- kernel 3: flash, ring-2, balanced 4-tile chunks ----------
// 1152 blocks = 8 b x 144 chunks. Chunk = up to 4 kv-tiles of one q-tile:
// q-tiles [4g, 4g+3] each own g+1 chunks (all non-empty; exactly covers
// ceil((qt+1)/4)). Block durations 1..4 iters -> balanced makespan
// (~16.5 mean iters/CU + <=4 tail) and 4.5 blocks/CU in flight (3 LDS-
// resident at 42 KB) for concurrent glds streams. Ring-2 stage-at-top:
// per iter {vmcnt(0)+barrier (drains loads issued a FULL iteration ago),
// stage j+1 into opposite buffer, compute j}.
__global__ __launch_bounds__(256) void flash_kernel(
        const unsigned short* __restrict__ qws, const unsigned short* __restrict__ kws,
        const unsigned short* __restrict__ vtws, const int* __restrict__ pmask,
        unsigned short* __restrict__ pO, float* __restrict__ pml) {
    __shared__ __align__(16) unsigned short Kt0[4096], Kt1[4096];
    __shared__ __align__(16) unsigned short Vt0[4096], Vt1[4096];
    __shared__ __align__(16) unsigned short Ps[4][1152];  // per-wave P [q16][kv 64+8]
    __shared__ __align__(16) float Bs[256];               // bias for <=4 iters

    const int t = threadIdx.x, blk = blockIdx.x;
    const int b = blk / 144, cid = blk - b * 144;
    // decode cid -> (qt, chunk): group g starts at 2g(g+1), spans 4(g+1)
    int g = 0;
    while (cid >= 2 * (g + 1) * (g + 2)) ++g;   // <=7 iters, block-uniform
    const int off = cid - 2 * g * (g + 1);
    const int qi = off / (g + 1);
    const int chunk = off - qi * (g + 1);
    const int qt = 4 * g + qi;
    const int jbeg = chunk * 4;
    int je = jbeg + 4; if (je > qt + 1) je = qt + 1;
    const int jend = je;
    const int niter = jend - jbeg;              // 1..4

    const int lane = t & 63, w = t >> 6;
    const int quad = lane >> 4, c = lane & 15;

    // staging geometry: instrs i0=2w, i1=2w+1 of 8; row = i*8 + (lane>>3)
    const int srow = lane >> 3, scb = (lane & 7) ^ srow;
    const unsigned short* kg0 = kws + (size_t)(b * TT + 2 * w * 8 + srow) * HS + scb * 8;
    const unsigned short* kg1 = kg0 + (size_t)8 * HS;
    const unsigned short* vg0 = vtws + (size_t)(b * 64 + 2 * w * 8 + srow) * TT + scb * 8;
    const unsigned short* vg1 = vg0 + (size_t)8 * TT;

#define FSTAGE(KD, VD, kv) \
    glds16(kg0 + (size_t)(kv) * HS, &KD[(2 * w + 0) * 512]); \
    glds16(kg1 + (size_t)(kv) * HS, &KD[(2 * w + 1) * 512]); \
    glds16(vg0 + (kv), &VD[(2 * w + 0) * 512]); \
    glds16(vg1 + (kv), &VD[(2 * w + 1) * 512]);

    // Q B-frag (n = qrow = c)
    bf16x8 qf[2];
#pragma unroll
    for (int kk = 0; kk < 2; ++kk)
        qf[kk] = ld_bf8(qws + (size_t)(b * TT + qt * 64 + w * 16 + c) * HS + kk * 32 + quad * 8);

    // fused bias: pad mask ints -> additive float bias in LDS
    {
        int bi = t * 4;
        if (bi < niter * 64) {
            i32x4 pmv = *(const i32x4*)(pmask + b * TT + jbeg * 64 + bi);
            f32x4 bvv;
#pragma unroll
            for (int j = 0; j < 4; ++j) bvv[j] = pmv[j] ? 0.0f : -1e30f;
            *(f32x4*)&Bs[bi] = bvv;
        }
    }

    // prologue: stage iter jbeg into buffer 0 (4 glds/wave in flight)
    FSTAGE(Kt0, Vt0, jbeg * 64)
    LGKM_BARRIER();   // Bs visible; glds drained by first VM0_BARRIER

    f32x4 o[4] = {};
    float m_run = -1e30f, l_run = 0.0f;
    const int ck7 = c & 7;

#define FITER(u, KT, VT, KD, VD) \
    if (j0 + (u) < jend) { \
        const int j = j0 + (u); \
        VM0_BARRIER(); \
        { int jn = j + 1; if (jn > jend - 1) jn = jend - 1; \
          FSTAGE(KD, VD, jn * 64) } \
        f32x4 bv[4]; \
        _Pragma("unroll") for (int nt = 0; nt < 4; ++nt) \
            bv[nt] = *(const f32x4*)&Bs[(j - jbeg) * 64 + nt * 16 + quad * 4]; \
        f32x4 s4[4] = {}; \
        _Pragma("unroll") for (int kk = 0; kk < 2; ++kk) \
        _Pragma("unroll") for (int nt = 0; nt < 4; ++nt) { \
            bf16x8 ka = ld_bf8(&KT[(nt * 16 + c) * 64 + (((kk * 4 + quad) ^ ck7) * 8)]); \
            s4[nt] = MFMA(ka, qf[kk], s4[nt]); } \
        if (j == qt) { \
            const int qrl = w * 16 + c; \
            _Pragma("unroll") for (int nt = 0; nt < 4; ++nt) \
            _Pragma("unroll") for (int r = 0; r < 4; ++r) { \
                int kvl = nt * 16 + quad * 4 + r; \
                s4[nt][r] = (kvl > qrl) ? -1e30f : (s4[nt][r] + bv[nt][r]); } \
        } else { \
            _Pragma("unroll") for (int nt = 0; nt < 4; ++nt) \
            _Pragma("unroll") for (int r = 0; r < 4; ++r) s4[nt][r] += bv[nt][r]; } \
        float mx = s4[0][0]; \
        _Pragma("unroll") for (int nt = 0; nt < 4; ++nt) \
        _Pragma("unroll") for (int r = 0; r < 4; ++r) mx = fmaxf(mx, s4[nt][r]); \
        mx = fmaxf(mx, __shfl_xor(mx, 16, 64)); \
        mx = fmaxf(mx, __shfl_xor(mx, 32, 64)); \
        float mnew = fmaxf(m_run, mx); \
        float al = exp2f(m_run - mnew); \
        m_run = mnew; \
        _Pragma("unroll") for (int nt = 0; nt < 4; ++nt) \
        _Pragma("unroll") for (int r = 0; r < 4; ++r) s4[nt][r] = exp2f(s4[nt][r] - mnew); \
        float rs = 0.0f; \
        _Pragma("unroll") for (int nt = 0; nt < 4; ++nt) \
            rs += (s4[nt][0] + s4[nt][1]) + (s4[nt][2] + s4[nt][3]); \
        rs += __shfl_xor(rs, 16, 64); \
        rs += __shfl_xor(rs, 32, 64); \
        l_run = l_run * al + rs; \
        _Pragma("unroll") for (int ht = 0; ht < 4; ++ht) \
        _Pragma("unroll") for (int r = 0; r < 4; ++r) o[ht][r] *= al; \
        _Pragma("unroll") for (int nt = 0; nt < 4; ++nt) { \
            u16x4 pk; \
            _Pragma("unroll") for (int r = 0; r < 4; ++r) pk[r] = cvt_bf16(s4[nt][r]); \
            *(u16x4*)&Ps[w][c * 72 + nt * 16 + quad * 4] = pk; } \
        bf16x8 p0 = ld_bf8(&Ps[w][c * 72 + quad * 8]); \
        bf16x8 p1 = ld_bf8(&Ps[w][c * 72 + 32 + quad * 8]); \
        _Pragma("unroll") for (int kk = 0; kk < 2; ++kk) { \
            bf16x8 pa = kk ? p1 : p0; \
            _Pragma("unroll") for (int ht = 0; ht < 4; ++ht) { \
                bf16x8 va = ld_bf8(&VT[(ht * 16 + c) * 64 + (((kk * 4 + quad) ^ ck7) * 8)]); \
                o[ht] = MFMA(va, pa, o[ht]); } } \
    }

    for (int j0 = jbeg; j0 < jend; j0 += 2) {
        FITER(0, Kt0, Vt0, Kt1, Vt1)
        FITER(1, Kt1, Vt1, Kt0, Vt0)
    }
#undef FITER
#undef FSTAGE

    VM_DRAIN();   // retire tail glds before LDS dealloc at endpgm

    // ---- store partials: slot = blk; pO [slot][row 64][h 64] ----
    unsigned short* po = pO + (size_t)blk * 4096;
#pragma unroll
    for (int ht = 0; ht < 4; ++ht) {
        u16x4 pk;
#pragma unroll
        for (int r = 0; r < 4; ++r) pk[r] = cvt_bf16(o[ht][r]);
        *(u16x4*)(po + (w * 16 + c) * 64 + ht * 16 + quad * 4) = pk;
    }
    if (quad == 0) {
        pml[(size_t)blk * 128 + (w * 16 + c) * 2] = m_run;
        pml[(size_t)blk * 128 + (w * 16 + c) * 2 + 1] = l_run;
    }
}

// ---------------- kernel 4: combine g+1 chunks, one thread per output -------
// 4096 blocks x 256 thr = 1M threads: gid -> (b, qt, row, h); h = lane so
// qt/nc are wave-uniform (no divergence). All <=8 chunk loads issued as a
// fully-unrolled predicated batch (static register indexing, 16 independent
// loads in flight) -> single latency exposure, hidden by TLP. One pass.
__global__ __launch_bounds__(256) void combine_kernel(
        const unsigned short* __restrict__ pO, const float* __restrict__ pml,
        float* __restrict__ out) {
    const int gid = blockIdx.x * 256 + threadIdx.x;
    const int h = gid & 63;
    const int grow = gid >> 6;            // global row 0..16383
    const int b = grow >> 11;
    const int rin = grow & 2047;
    const int qt = rin >> 6;
    const int row = rin & 63;
    const int g = qt >> 2;
    const int nc = g + 1;                 // 1..8 chunks, wave-uniform
    const int s0 = b * 144 + 2 * g * (g + 1) + (qt - 4 * g) * (g + 1);

    float m_[8], l_[8], o_[8];
#pragma unroll
    for (int s = 0; s < 8; ++s) {
        const int slot = s0 + (s < nc ? s : 0);   // clamp: predicated out below
        const float2 ml = *(const float2*)(pml + (size_t)slot * 128 + row * 2);
        const float ov = bf2f(pO[(size_t)slot * 4096 + row * 64 + h]);
        m_[s] = (s < nc) ? ml.x : -3.0e38f;
        l_[s] = (s < nc) ? ml.y : 0.0f;
        o_[s] = (s < nc) ? ov : 0.0f;
    }
    float M = m_[0];
#pragma unroll
    for (int s = 1; s < 8; ++s) M = fmaxf(M, m_[s]);
    float num = 0.0f, den = 0.0f;
#pragma unroll
    for (int s = 0; s < 8; ++s) {
        const float ww = exp2f(m_[s] - M);    // invalid slots -> exp2(-huge)=0
        num += o_[s] * ww;
        den += l_[s] * ww;
    }
    out[(size_t)(b * TT + qt * 64 + row) * HS + h] = num / den;
}

extern "C" void kernel_launch(void* const* d_in, const int* in_sizes, int n_in,
                              void* d_out, int out_size, void* d_ws, size_t ws_size,
                              hipStream_t stream) {
    const float* x  = (const float*)d_in[0];
    const int* pm   = (const int*)d_in[1];
    const float* Wq = (const float*)d_in[2];
    const float* Wk = (const float*)d_in[3];
    const float* Wv = (const float*)d_in[4];
    float* out = (float*)d_out;

    unsigned short* wsu  = (unsigned short*)d_ws;
    unsigned short* wbt  = wsu + WBT_E;
    unsigned short* qws  = wsu + Q_E;
    unsigned short* kws  = wsu + K_E;
    unsigned short* vtws = wsu + VT_E;
    unsigned short* pO   = wsu + PO_E;
    float* pml           = (float*)(wsu + PML_E);

    wconv_kernel<<<48, 256, 0, stream>>>(Wq, Wk, Wv, wbt);
    proj_kernel<<<256, 512, 0, stream>>>(x, wbt, qws, kws, vtws);
    flash_kernel<<<1152, 256, 0, stream>>>(qws, kws, vtws, pm, pO, pml);
    combine_kernel<<<4096, 256, 0, stream>>>(pO, pml, out);
}